// Round 6
// baseline (3035.370 us; speedup 1.0000x reference)
//
#include <hip/hip_runtime.h>
#include <math.h>

#define NTOT  65536
#define DLAT  256
#define KCB   4096
#define CIN   256
#define HWSZ  4096
#define NSPLIT 2

// workspace float offsets
#define OFF_ZPT   0u            // [256][65536] f32
#define OFF_EMBT  16777216u     // [256][4096]  f32
#define OFF_WT    17825792u     // [256][256]   f32
#define OFF_ENORM 17891328u     // [4096]       f32
#define OFF_RNORM 17895424u     // [65536]      f32
#define OFF_IDX   17960960u     // [65536]      i32
#define OFF_CD    18026496u     // [NSPLIT][65536] f32 per-split best dist
#define OFF_CI    18288640u     // [NSPLIT][65536] i32 per-split best idx

typedef unsigned int u32;

#define GLD16(gsrc, ldst) __builtin_amdgcn_global_load_lds( \
    (const __attribute__((address_space(1))) u32*)(gsrc), \
    (__attribute__((address_space(3))) u32*)(ldst), 16, 0, 0)

__global__ __launch_bounds__(256) void wt_kernel(const float* __restrict__ w, float* __restrict__ wT) {
    int t = blockIdx.x * 256 + threadIdx.x;     // 65536
    int o = t >> 8, c = t & 255;
    wT[c * 256 + o] = w[t];
}

__global__ __launch_bounds__(256) void et_kernel(const float* __restrict__ emb, float* __restrict__ embT) {
    int t = blockIdx.x * 256 + threadIdx.x;     // 1048576
    int k = t >> 8, d = t & 255;
    embT[d * KCB + k] = emb[t];
}

__global__ __launch_bounds__(64) void enorm_kernel(const float* __restrict__ emb, float* __restrict__ enorm) {
    int k = blockIdx.x;
    int lane = threadIdx.x;
    double a = 0.0;
    #pragma unroll
    for (int i = 0; i < 4; ++i) {
        float v = emb[k * DLAT + lane + i * 64];
        a = fma((double)v, (double)v, a);
    }
    #pragma unroll
    for (int off = 32; off > 0; off >>= 1) a += __shfl_down(a, off);
    if (lane == 0) enorm[k] = (float)a;   // single rounding to f32
}

__global__ __launch_bounds__(256) void rnorm_kernel(const float* __restrict__ zpT, float* __restrict__ rnorm) {
    int n = blockIdx.x * 256 + threadIdx.x;
    double a = 0.0;
    for (int o = 0; o < DLAT; ++o) {
        float v = zpT[(size_t)o * NTOT + n];
        a = fma((double)v, (double)v, a);
    }
    rnorm[n] = (float)a;                  // single rounding to f32
}

// zpT[o][n] = sum_c z[b][c][hw] * wT[c][o] + bias[o]
__global__ __launch_bounds__(256) void proj_kernel(const float* __restrict__ z, const float* __restrict__ wT,
                                                   const float* __restrict__ bias, float* __restrict__ zpT) {
    __shared__ float zT[16][128];
    __shared__ float wt[16][64];
    int n0 = blockIdx.x * 128;
    int o0 = blockIdx.y * 64;
    int t = threadIdx.x;
    int tm = t & 15, tn = t >> 4;
    int b = n0 >> 12;
    int hw0 = n0 & 4095;
    float acc[8][4] = {};
    for (int c0 = 0; c0 < CIN; c0 += 16) {
        __syncthreads();
        #pragma unroll
        for (int i = 0; i < 2; ++i) {
            int e4 = t + i * 256;
            int cc = e4 >> 5, c4 = e4 & 31;
            float4 v = *(const float4*)(z + (size_t)(b * CIN + c0 + cc) * HWSZ + hw0 + c4 * 4);
            *(float4*)&zT[cc][c4 * 4] = v;
        }
        {
            int cc = t >> 4, c4 = t & 15;
            float4 v = *(const float4*)(wT + (size_t)(c0 + cc) * 256 + o0 + c4 * 4);
            *(float4*)&wt[cc][c4 * 4] = v;
        }
        __syncthreads();
        #pragma unroll
        for (int d = 0; d < 16; ++d) {
            float4 a0 = *(const float4*)&zT[d][tm * 8];
            float4 a1 = *(const float4*)&zT[d][tm * 8 + 4];
            float4 bv = *(const float4*)&wt[d][tn * 4];
            float a[8] = {a0.x,a0.y,a0.z,a0.w,a1.x,a1.y,a1.z,a1.w};
            float bb[4] = {bv.x,bv.y,bv.z,bv.w};
            #pragma unroll
            for (int i = 0; i < 8; ++i)
                #pragma unroll
                for (int j = 0; j < 4; ++j)
                    acc[i][j] = fmaf(a[i], bb[j], acc[i][j]);
        }
    }
    #pragma unroll
    for (int j = 0; j < 4; ++j) {
        int o = o0 + tn * 4 + j;
        float bv = bias[o];
        #pragma unroll
        for (int i = 0; i < 8; ++i) {
            int n = n0 + tm * 8 + i;
            zpT[(size_t)o * NTOT + n] = acc[i][j] + bv;
        }
    }
}

// Fused distance + argmin. Block = 64 rows x 128-code k-steps, 2-way k-split
// via blockIdx.y. Thread (tm,tn): 4 rows {tm*4+i} x 8 codes {tn*8+j}.
// acc[32]+c[32] fits the 128-VGPR budget (launch_bounds 256,4) so the
// compiler does NOT re-tile (r4's 8x8 exceeded 108 VGPR -> implicit respill).
// Staging: global_load_lds direct (dest lane-linear t*16B), 2-phase template:
// STAGE(next buf) -> compute(cur) -> vmcnt(0) -> s_barrier. One barrier/chunk.
// Per-(row,code) arithmetic chain bitwise-identical to the verified kernels:
// 16-d fmaf partials from 0 folded ascending; dist=(rn-2*acc)+en; strict <
// ascending k; cross-thread merge ties on lower idx; cross-split merge strict <.
__global__ __launch_bounds__(256, 4) void argmin_kernel(const float* __restrict__ zpT, const float* __restrict__ embT,
                                                        const float* __restrict__ enorm, const float* __restrict__ rnorm,
                                                        float* __restrict__ cand_d, int* __restrict__ cand_i) {
    __shared__ float zA[2][16][64];    // A: 16 d x 64 rows
    __shared__ float zB[2][16][128];   // B: 16 d x 128 codes
    __shared__ float rv[64][17];
    __shared__ int   ri[64][17];
    const int t = threadIdx.x;
    const int tm = t & 15, tn = t >> 4;
    const int n0 = blockIdx.x * 64;
    const int kbase0 = blockIdx.y * 2048;
    // staging geometry (lane-linear: LDS byte offset == t*16)
    const int aRow = t >> 4, aCol = (t & 15) * 4;    // zA[16][64]
    const int bRow = t >> 5, bCol = (t & 31) * 4;    // zB[16][128], 2 halves
    const int wb = (t & ~63) * 16;                   // wave-uniform LDS byte base

    float rn[4];
    #pragma unroll
    for (int i = 0; i < 4; ++i) rn[i] = rnorm[n0 + tm * 4 + i];
    float best[4]; int bidx[4];
    #pragma unroll
    for (int i = 0; i < 4; ++i) { best[i] = INFINITY; bidx[i] = 0; }
    float acc[32];

    // prologue: stage u=0 into buf 0  (d0=0, k0=kbase0)
    {
        char* dA = (char*)&zA[0][0][0] + wb;
        char* dB = (char*)&zB[0][0][0] + wb;
        GLD16(zpT + ((size_t)aRow << 16) + n0 + aCol, dA);
        GLD16(embT + ((size_t)bRow << 12) + kbase0 + bCol, dB);
        GLD16(embT + ((size_t)(8 + bRow) << 12) + kbase0 + bCol, dB + 4096);
    }
    asm volatile("s_waitcnt vmcnt(0)" ::: "memory");
    __builtin_amdgcn_s_barrier();
    __builtin_amdgcn_sched_barrier(0);

    for (int u = 0; u < 256; ++u) {    // u = kstep*16 + chunk
        const int p = u & 1;
        if ((u & 15) == 0) {
            #pragma unroll
            for (int x = 0; x < 32; ++x) acc[x] = 0.0f;
        }
        if (u < 255) {                 // stage u+1 into buf p^1 (issue early)
            const int un = u + 1;
            const int d0n = (un & 15) << 4;
            const size_t k0n = (size_t)kbase0 + (size_t)((un >> 4) << 7);
            char* dA = (char*)&zA[p ^ 1][0][0] + wb;
            char* dB = (char*)&zB[p ^ 1][0][0] + wb;
            GLD16(zpT + ((size_t)(d0n + aRow) << 16) + n0 + aCol, dA);
            GLD16(embT + ((size_t)(d0n + bRow) << 12) + k0n + bCol, dB);
            GLD16(embT + ((size_t)(d0n + 8 + bRow) << 12) + k0n + bCol, dB + 4096);
        }
        // compute current chunk (16 d) from buf p
        float c[32];
        #pragma unroll
        for (int x = 0; x < 32; ++x) c[x] = 0.0f;
        #pragma unroll
        for (int dd = 0; dd < 16; ++dd) {
            const float4 a  = *(const float4*)&zA[p][dd][tm * 4];
            const float4 b0 = *(const float4*)&zB[p][dd][tn * 8];
            const float4 b1 = *(const float4*)&zB[p][dd][tn * 8 + 4];
#define FMA_ROW(i, av) \
            c[i*8+0]=fmaf(av,b0.x,c[i*8+0]); c[i*8+1]=fmaf(av,b0.y,c[i*8+1]); \
            c[i*8+2]=fmaf(av,b0.z,c[i*8+2]); c[i*8+3]=fmaf(av,b0.w,c[i*8+3]); \
            c[i*8+4]=fmaf(av,b1.x,c[i*8+4]); c[i*8+5]=fmaf(av,b1.y,c[i*8+5]); \
            c[i*8+6]=fmaf(av,b1.z,c[i*8+6]); c[i*8+7]=fmaf(av,b1.w,c[i*8+7]);
            FMA_ROW(0, a.x) FMA_ROW(1, a.y) FMA_ROW(2, a.z) FMA_ROW(3, a.w)
#undef FMA_ROW
        }
        #pragma unroll
        for (int x = 0; x < 32; ++x) acc[x] += c[x];
        if ((u & 15) == 15) {          // epilogue for this k-step
            const int k0 = kbase0 + ((u >> 4) << 7);
            #pragma unroll
            for (int j = 0; j < 8; ++j) {
                const int g = k0 + tn * 8 + j;
                const float en = enorm[g];
                #pragma unroll
                for (int i = 0; i < 4; ++i) {
                    const float dv = (rn[i] - 2.0f * acc[i * 8 + j]) + en;
                    if (dv < best[i]) { best[i] = dv; bidx[i] = g; }
                }
            }
        }
        asm volatile("s_waitcnt vmcnt(0)" ::: "memory");
        __builtin_amdgcn_s_barrier();
        __builtin_amdgcn_sched_barrier(0);
    }

    __syncthreads();
    #pragma unroll
    for (int i = 0; i < 4; ++i) {
        rv[tm * 4 + i][tn] = best[i];
        ri[tm * 4 + i][tn] = bidx[i];
    }
    __syncthreads();
    if (t < 64) {
        float bv = rv[t][0]; int bi = ri[t][0];
        #pragma unroll
        for (int q = 1; q < 16; ++q) {
            float v = rv[t][q]; int iq = ri[t][q];
            if (v < bv || (v == bv && iq < bi)) { bv = v; bi = iq; }
        }
        cand_d[blockIdx.y * NTOT + n0 + t] = bv;
        cand_i[blockIdx.y * NTOT + n0 + t] = bi;
    }
}

__global__ __launch_bounds__(256) void merge_kernel(const float* __restrict__ cand_d, const int* __restrict__ cand_i,
                                                    int* __restrict__ idx) {
    int n = blockIdx.x * 256 + threadIdx.x;
    float bv = cand_d[n];
    int bi = cand_i[n];
    #pragma unroll
    for (int s = 1; s < NSPLIT; ++s) {
        float v = cand_d[s * NTOT + n];
        int iv = cand_i[s * NTOT + n];
        if (v < bv) { bv = v; bi = iv; }   // strict <: earlier split = lower k wins ties
    }
    idx[n] = bi;
}

// out[b][o][hw] = zp + (emb[idx][o] - zp)   (straight-through, f32-faithful)
__global__ __launch_bounds__(256) void out_kernel(const float* __restrict__ zpT, const float* __restrict__ emb,
                                                  const int* __restrict__ idx, float* __restrict__ out) {
    int e = blockIdx.x * 256 + threadIdx.x;
    int hw = e & 4095;
    int o = (e >> 12) & 255;
    int b = e >> 20;
    int n = (b << 12) | hw;
    float zp = zpT[(size_t)o * NTOT + n];
    float ev = emb[idx[n] * DLAT + o];
    float st = ev - zp;
    out[e] = zp + st;
}

extern "C" void kernel_launch(void* const* d_in, const int* in_sizes, int n_in,
                              void* d_out, int out_size, void* d_ws, size_t ws_size,
                              hipStream_t stream) {
    const float* z    = (const float*)d_in[0];
    const float* w    = (const float*)d_in[1];
    const float* bias = (const float*)d_in[2];
    const float* emb  = (const float*)d_in[3];
    float* ws = (float*)d_ws;
    float* zpT   = ws + OFF_ZPT;
    float* embT  = ws + OFF_EMBT;
    float* wT    = ws + OFF_WT;
    float* enorm = ws + OFF_ENORM;
    float* rnorm = ws + OFF_RNORM;
    int*   idx   = (int*)(ws + OFF_IDX);
    float* cand_d = ws + OFF_CD;
    int*   cand_i = (int*)(ws + OFF_CI);
    float* out   = (float*)d_out;

    hipLaunchKernelGGL(wt_kernel,     dim3(256),        dim3(256), 0, stream, w, wT);
    hipLaunchKernelGGL(et_kernel,     dim3(4096),       dim3(256), 0, stream, emb, embT);
    hipLaunchKernelGGL(enorm_kernel,  dim3(4096),       dim3(64),  0, stream, emb, enorm);
    hipLaunchKernelGGL(proj_kernel,   dim3(512, 4),     dim3(256), 0, stream, z, wT, bias, zpT);
    hipLaunchKernelGGL(rnorm_kernel,  dim3(256),        dim3(256), 0, stream, zpT, rnorm);
    hipLaunchKernelGGL(argmin_kernel, dim3(1024, NSPLIT), dim3(256), 0, stream, zpT, embT, enorm, rnorm, cand_d, cand_i);
    hipLaunchKernelGGL(merge_kernel,  dim3(256),        dim3(256), 0, stream, cand_d, cand_i, idx);
    hipLaunchKernelGGL(out_kernel,    dim3(65536),      dim3(256), 0, stream, zpT, emb, idx, out);
}